// Round 1
// baseline (6372.595 us; speedup 1.0000x reference)
//
#include <hip/hip_runtime.h>
#include <cstdint>

constexpr int BB = 128;   // batch
constexpr int SS = 512;   // source length
constexpr int DD = 512;   // hidden dim
constexpr int TT = 64;    // decode steps
constexpr int OO = 3;     // output dim

constexpr float C2LE = 2.8853900817779268f;  // 2*log2(e)

typedef __attribute__((ext_vector_type(8))) short bf16x8;
typedef __attribute__((ext_vector_type(4))) float f32x4;

__device__ __forceinline__ float tanh_fast(float x) {
  float e = __expf(2.0f * x);
  return 1.0f - 2.0f / (e + 1.0f);
}
__device__ __forceinline__ float sigmoid_fast(float x) {
  return 1.0f / (1.0f + __expf(-x));
}
__device__ __forceinline__ unsigned short f2bf(float f) {
  uint32_t u = __float_as_uint(f);
  uint32_t r = (u + 0x7FFFu + ((u >> 16) & 1u)) >> 16;  // RNE
  return (unsigned short)r;
}
__device__ __forceinline__ float2 bfx2(uint32_t u) {
  float2 r;
  r.x = __uint_as_float(u << 16);
  r.y = __uint_as_float(u & 0xFFFF0000u);
  return r;
}
__device__ __forceinline__ float fexp2(float x) {
#if __has_builtin(__builtin_amdgcn_exp2f)
  return __builtin_amdgcn_exp2f(x);
#else
  return exp2f(x);
#endif
}
__device__ __forceinline__ float frcp(float x) {
#if __has_builtin(__builtin_amdgcn_rcpf)
  return __builtin_amdgcn_rcpf(x);
#else
  return 1.0f / x;
#endif
}

// ---------------------------------------------------------------------------
// MFMA bf16 GEMM: Uk2 = bf16( C2LE * (e_bf @ Ua_bf^T + bu) )   [B*S x D]
// 128x128 block tile, 4 waves each 64x64 (4x4 of 16x16x32 MFMA).
// ---------------------------------------------------------------------------
__global__ __launch_bounds__(256) void gemm_uk_mfma(
    const unsigned short* __restrict__ A, const unsigned short* __restrict__ Bw,
    const float* __restrict__ bias, unsigned short* __restrict__ Uk) {
  __shared__ unsigned short Asb[128 * 40];
  __shared__ unsigned short Bsb[128 * 40];
  const int tid = threadIdx.x;
  const int m0 = blockIdx.y * 128, n0 = blockIdx.x * 128;
  const int w = tid >> 6, l = tid & 63;
  const int wr = w >> 1, wc = w & 1;
  const int lm = l & 15, kg = l >> 4;

  f32x4 acc[4][4] = {};

  for (int kc = 0; kc < 512; kc += 32) {
    uint4 av[2], bv[2];
#pragma unroll
    for (int p = 0; p < 2; ++p) {
      int u = tid + p * 256;
      int r = u >> 2, ko = (u & 3) * 8;
      av[p] = *(const uint4*)(A + (size_t)(m0 + r) * 512 + kc + ko);
      bv[p] = *(const uint4*)(Bw + (size_t)(n0 + r) * 512 + kc + ko);
    }
    __syncthreads();
#pragma unroll
    for (int p = 0; p < 2; ++p) {
      int u = tid + p * 256;
      int r = u >> 2, ko = (u & 3) * 8;
      *(uint4*)&Asb[r * 40 + ko] = av[p];
      *(uint4*)&Bsb[r * 40 + ko] = bv[p];
    }
    __syncthreads();
    bf16x8 af[4], bfr[4];
#pragma unroll
    for (int i = 0; i < 4; ++i) {
      af[i]  = *(const bf16x8*)&Asb[(wr * 64 + i * 16 + lm) * 40 + kg * 8];
      bfr[i] = *(const bf16x8*)&Bsb[(wc * 64 + i * 16 + lm) * 40 + kg * 8];
    }
#pragma unroll
    for (int i = 0; i < 4; ++i)
#pragma unroll
      for (int j = 0; j < 4; ++j)
        acc[i][j] = __builtin_amdgcn_mfma_f32_16x16x32_bf16(af[i], bfr[j],
                                                            acc[i][j], 0, 0, 0);
  }

  const int row_base = m0 + wr * 64;
  const int col_base = n0 + wc * 64;
#pragma unroll
  for (int j = 0; j < 4; ++j) {
    const int col = col_base + j * 16 + lm;
    const float bu = bias[col];
#pragma unroll
    for (int i = 0; i < 4; ++i) {
      const int r0 = row_base + i * 16 + kg * 4;
#pragma unroll
      for (int rr = 0; rr < 4; ++rr)
        Uk[(size_t)(r0 + rr) * 512 + col] = f2bf(C2LE * (acc[i][j][rr] + bu));
    }
  }
}

// fp32 -> bf16, 8 elems/thread
__global__ __launch_bounds__(256) void conv_bf(const float* __restrict__ in,
                                               unsigned short* __restrict__ outp) {
  size_t idx = ((size_t)blockIdx.x * 256 + threadIdx.x) * 8;
  const float4* p = (const float4*)(in + idx);
  float4 a = p[0], b = p[1];
  uint4 r;
  r.x = f2bf(a.x) | ((uint32_t)f2bf(a.y) << 16);
  r.y = f2bf(a.z) | ((uint32_t)f2bf(a.w) << 16);
  r.z = f2bf(b.x) | ((uint32_t)f2bf(b.y) << 16);
  r.w = f2bf(b.z) | ((uint32_t)f2bf(b.w) << 16);
  *(uint4*)(outp + idx) = r;
}

// Wcat packed uint32[512 k][1024 col-pairs]: col j<512 -> C2LE*Wa[j][k] (q2),
// col j>=512 -> W_hh[j-512][k] (gh).
__global__ void prep_wcat(const float* __restrict__ Wa,
                          const float* __restrict__ Whh,
                          uint32_t* __restrict__ Wcat) {
  int idx = blockIdx.x * 256 + threadIdx.x;  // 512*1024
  int k = idx >> 10, j2 = idx & 1023;
  int j0 = 2 * j2;
  float v0 = (j0 < DD) ? Wa[(size_t)j0 * DD + k] * C2LE
                       : Whh[(size_t)(j0 - DD) * DD + k];
  float v1 = (j0 + 1 < DD) ? Wa[(size_t)(j0 + 1) * DD + k] * C2LE
                           : Whh[(size_t)(j0 + 1 - DD) * DD + k];
  Wcat[idx] = (uint32_t)f2bf(v0) | ((uint32_t)f2bf(v1) << 16);
}

__global__ void prep_bcat(const float* __restrict__ ba,
                          const float* __restrict__ bhh,
                          float* __restrict__ bcat) {
  int j = blockIdx.x * 256 + threadIdx.x;  // 2048
  bcat[j] = (j < DD) ? ba[j] * C2LE : bhh[j - DD];
}

// Wih2 packed uint32[512 k][768 col-pairs]: cols of W_ih[:, :512]^T (bf16)
__global__ void prep_wih(const float* __restrict__ W_ih,
                         uint32_t* __restrict__ Wih2) {
  int idx = blockIdx.x * 256 + threadIdx.x;  // 512*768
  int k = idx / 768, j2 = idx % 768;
  int j0 = 2 * j2;
  float v0 = W_ih[(size_t)j0 * (DD + OO) + k];
  float v1 = W_ih[(size_t)(j0 + 1) * (DD + OO) + k];
  Wih2[(size_t)k * 768 + j2] = (uint32_t)f2bf(v0) | ((uint32_t)f2bf(v1) << 16);
}

// [q2 | gh] = hn @ Wcat + bcat  (matvec, all 1024 threads, 2 cols each)
__device__ __forceinline__ void qgh_phase(const float* h_sh,
                                          const uint32_t* __restrict__ Wcat,
                                          const float* __restrict__ bcat,
                                          float* q2_sh, float* gh_sh, int tid) {
  float ax = 0.f, ay = 0.f;
  for (int k0 = 0; k0 < DD; k0 += 8) {
    float hk[8];
    *(float4*)&hk[0] = *(const float4*)&h_sh[k0];
    *(float4*)&hk[4] = *(const float4*)&h_sh[k0 + 4];
#pragma unroll
    for (int kk = 0; kk < 8; ++kk) {
      float2 w2 = bfx2(Wcat[(size_t)(k0 + kk) * 1024 + tid]);
      ax += hk[kk] * w2.x;
      ay += hk[kk] * w2.y;
    }
  }
  const int j0 = 2 * tid;
  ax += bcat[j0];
  ay += bcat[j0 + 1];
  if (j0 < DD) {
    q2_sh[j0] = ax;
    q2_sh[j0 + 1] = ay;
  } else {
    gh_sh[j0 - DD] = ax;
    gh_sh[j0 + 1 - DD] = ay;
  }
}

// ---------------------------------------------------------------------------
// Persistent decode: one block per batch element, entire T-loop in-kernel.
// All intermediates in LDS; only inputs/weights/outputs touch global.
// ---------------------------------------------------------------------------
__global__ __launch_bounds__(1024, 1) void decode_persistent(
    const unsigned short* __restrict__ Uk2, const unsigned short* __restrict__ e_bf,
    const uint32_t* __restrict__ Wcat, const float* __restrict__ bcat,
    const uint32_t* __restrict__ Wih2, const float* __restrict__ b_ih,
    const float* __restrict__ W_ih, const float* __restrict__ e_last,
    const float* __restrict__ target, const float* __restrict__ Va_w,
    const float* __restrict__ W_out, const float* __restrict__ b_out,
    float* __restrict__ out_d, float* __restrict__ out_hT,
    float* __restrict__ out_attn) {
  const int b = blockIdx.x, tid = threadIdx.x;

  __shared__ float h_s[DD];
  __shared__ float q2_s[DD];
  __shared__ float va_s[DD];
  __shared__ float sc_s[SS];
  __shared__ float w_s[SS];
  __shared__ float ctx_s[DD];
  __shared__ float gi_s[3 * DD];
  __shared__ float gh_s[3 * DD];
  __shared__ float red_s[32];
  __shared__ float part_s[16 * 520];  // ctx partials, pitch 520 (conflict-free read)

  // ---- init: h = e_last[b]; va cached; initial q2, gh
  if (tid < DD) {
    h_s[tid] = e_last[(size_t)b * DD + tid];
    va_s[tid] = Va_w[tid];
  }
  __syncthreads();
  qgh_phase(h_s, Wcat, bcat, q2_s, gh_s, tid);
  __syncthreads();

  for (int t = 0; t < TT; ++t) {
    // ---- P1: scores'[s] = sum_d va[d] / (1 + 2^(q2[d]+Uk2[b,s,d]))
    // (true scores = const - 2*scores'; const cancels in softmax)
    {
      const int s = tid >> 1, hf = tid & 1;
      const uint4* up =
          (const uint4*)(Uk2 + ((size_t)b * SS + s) * DD + hf * 256);
      const float4* qp = (const float4*)&q2_s[hf * 256];
      const float4* vp = (const float4*)&va_s[hf * 256];
      float acc = 0.f;
#pragma unroll 4
      for (int j = 0; j < 32; ++j) {
        uint4 u = up[j];
        float4 q0 = qp[2 * j], q1 = qp[2 * j + 1];
        float4 v0 = vp[2 * j], v1 = vp[2 * j + 1];
        float2 e0 = bfx2(u.x), e1 = bfx2(u.y), e2 = bfx2(u.z), e3 = bfx2(u.w);
        acc += v0.x * frcp(1.f + fexp2(q0.x + e0.x));
        acc += v0.y * frcp(1.f + fexp2(q0.y + e0.y));
        acc += v0.z * frcp(1.f + fexp2(q0.z + e1.x));
        acc += v0.w * frcp(1.f + fexp2(q0.w + e1.y));
        acc += v1.x * frcp(1.f + fexp2(q1.x + e2.x));
        acc += v1.y * frcp(1.f + fexp2(q1.y + e2.y));
        acc += v1.z * frcp(1.f + fexp2(q1.z + e3.x));
        acc += v1.w * frcp(1.f + fexp2(q1.w + e3.y));
      }
      acc += __shfl_xor(acc, 1);
      if (hf == 0) sc_s[s] = acc;
    }
    __syncthreads();

    // ---- P2: softmax over y = -2*sc ; write w_s and out_attn
    float yv = 0.f, ev = 0.f;
    {
      float m = -1e30f;
      if (tid < SS) {
        yv = -2.f * sc_s[tid];
        m = yv;
      }
#pragma unroll
      for (int off = 32; off; off >>= 1) m = fmaxf(m, __shfl_xor(m, off));
      if ((tid & 63) == 0) red_s[tid >> 6] = m;
    }
    __syncthreads();
    {
      float gm = red_s[0];
#pragma unroll
      for (int i = 1; i < 8; ++i) gm = fmaxf(gm, red_s[i]);
      float sm = 0.f;
      if (tid < SS) {
        ev = __expf(yv - gm);
        sm = ev;
      }
#pragma unroll
      for (int off = 32; off; off >>= 1) sm += __shfl_xor(sm, off);
      if ((tid & 63) == 0) red_s[16 + (tid >> 6)] = sm;
    }
    __syncthreads();
    {
      float tot = red_s[16];
#pragma unroll
      for (int i = 1; i < 8; ++i) tot += red_s[16 + i];
      if (tid < SS) {
        float wv = ev * frcp(tot);
        w_s[tid] = wv;
        out_attn[((size_t)b * TT + t) * SS + tid] = wv;
      }
    }
    __syncthreads();

    // ---- P3: ctx[d] = sum_s w[s]*e[b,s,d]  (16 waves x 32 s, 64 d-slots)
    {
      const int wv = tid >> 6, ln = tid & 63;
      const unsigned short* eb = e_bf + (size_t)b * SS * DD + ln * 8;
      float a0 = 0.f, a1 = 0.f, a2 = 0.f, a3 = 0.f;
      float a4 = 0.f, a5 = 0.f, a6 = 0.f, a7 = 0.f;
#pragma unroll 4
      for (int si = 0; si < 32; ++si) {
        const int s = wv * 32 + si;
        uint4 u = *(const uint4*)(eb + (size_t)s * DD);
        float ws = w_s[s];
        float2 p0 = bfx2(u.x), p1 = bfx2(u.y), p2 = bfx2(u.z), p3 = bfx2(u.w);
        a0 += ws * p0.x; a1 += ws * p0.y;
        a2 += ws * p1.x; a3 += ws * p1.y;
        a4 += ws * p2.x; a5 += ws * p2.y;
        a6 += ws * p3.x; a7 += ws * p3.y;
      }
      float4 lo = {a0, a1, a2, a3}, hi = {a4, a5, a6, a7};
      *(float4*)&part_s[wv * 520 + ln * 8] = lo;
      *(float4*)&part_s[wv * 520 + ln * 8 + 4] = hi;
    }
    __syncthreads();
    if (tid < DD) {
      float r = 0.f;
#pragma unroll
      for (int sg = 0; sg < 16; ++sg) r += part_s[sg * 520 + tid];
      ctx_s[tid] = r;
    }
    __syncthreads();

    // ---- P4: gi = ctx @ W_ih[:, :512]^T + b_ih  (768 threads, 2 cols each)
    if (tid < 768) {
      float ax = 0.f, ay = 0.f;
      for (int k0 = 0; k0 < DD; k0 += 8) {
        float ck[8];
        *(float4*)&ck[0] = *(const float4*)&ctx_s[k0];
        *(float4*)&ck[4] = *(const float4*)&ctx_s[k0 + 4];
#pragma unroll
        for (int kk = 0; kk < 8; ++kk) {
          float2 w2 = bfx2(Wih2[(size_t)(k0 + kk) * 768 + tid]);
          ax += ck[kk] * w2.x;
          ay += ck[kk] * w2.y;
        }
      }
      gi_s[2 * tid] = ax + b_ih[2 * tid];
      gi_s[2 * tid + 1] = ay + b_ih[2 * tid + 1];
    }
    __syncthreads();

    // ---- P5: GRU pointwise update (threads < 512)
    if (tid < DD) {
      const int d = tid;
      float x0 = 0.f, x1 = 0.f, x2 = 0.f;
      if (t > 0) {
        const float* xp = target + ((size_t)b * TT + (t - 1)) * OO;
        x0 = xp[0]; x1 = xp[1]; x2 = xp[2];
      }
      const float* w0 = W_ih + (size_t)d * (DD + OO) + DD;
      const float* w1 = W_ih + (size_t)(DD + d) * (DD + OO) + DD;
      const float* w2 = W_ih + (size_t)(2 * DD + d) * (DD + OO) + DD;
      float ir  = gi_s[d]          + x0 * w0[0] + x1 * w0[1] + x2 * w0[2];
      float iz  = gi_s[DD + d]     + x0 * w1[0] + x1 * w1[1] + x2 * w1[2];
      float in_ = gi_s[2 * DD + d] + x0 * w2[0] + x1 * w2[1] + x2 * w2[2];
      float r = sigmoid_fast(ir + gh_s[d]);
      float z = sigmoid_fast(iz + gh_s[DD + d]);
      float n = tanh_fast(in_ + r * gh_s[2 * DD + d]);
      float hnew = (1.f - z) * n + z * h_s[d];
      h_s[d] = hnew;
      if (t == TT - 1) out_hT[(size_t)b * DD + d] = hnew;
    }
    __syncthreads();

    // ---- P5b: output projection (3 waves), P6: next-step q2/gh (all threads)
    if (tid < 192) {
      const int wid = tid >> 6, ln = tid & 63;
      const float* wrow = W_out + (size_t)wid * DD;
      float acc = 0.f;
      for (int i = ln; i < DD; i += 64) acc += h_s[i] * wrow[i];
#pragma unroll
      for (int off = 32; off; off >>= 1) acc += __shfl_xor(acc, off);
      if (ln == 0) out_d[((size_t)b * TT + t) * OO + wid] = acc + b_out[wid];
    }
    qgh_phase(h_s, Wcat, bcat, q2_s, gh_s, tid);
    __syncthreads();
  }
}

// ---------------------------------------------------------------------------
extern "C" void kernel_launch(void* const* d_in, const int* in_sizes, int n_in,
                              void* d_out, int out_size, void* d_ws, size_t ws_size,
                              hipStream_t stream) {
  const float* e_all  = (const float*)d_in[0];
  const float* e_last = (const float*)d_in[1];
  const float* target = (const float*)d_in[2];
  const float* Wa     = (const float*)d_in[3];
  const float* ba     = (const float*)d_in[4];
  const float* Ua     = (const float*)d_in[5];
  const float* bu     = (const float*)d_in[6];
  const float* Va_w   = (const float*)d_in[7];
  const float* W_ih   = (const float*)d_in[9];
  const float* b_ih   = (const float*)d_in[10];
  const float* W_hh   = (const float*)d_in[11];
  const float* b_hh   = (const float*)d_in[12];
  const float* W_out  = (const float*)d_in[13];
  const float* b_out  = (const float*)d_in[14];

  float* out      = (float*)d_out;
  float* out_d    = out;                         // [B,T,3]
  float* out_hT   = out + (size_t)BB * TT * OO;  // [1,B,D]
  float* out_attn = out_hT + (size_t)BB * DD;    // [B,T,S]

  // Workspace layout (total 138,420,224 B <= 139,479,040 B proven-safe):
  char* wsB = (char*)d_ws;
  const size_t szUk = (size_t)BB * SS * DD * 2;        // 67,108,864
  unsigned short* Uk2   = (unsigned short*)wsB;
  unsigned short* e_bfp = (unsigned short*)(wsB + szUk);
  uint32_t* Wcat = (uint32_t*)(wsB + 2 * szUk);                        // 2,097,152
  uint32_t* Wih2 = (uint32_t*)(wsB + 2 * szUk + (size_t)DD * 1024 * 4);  // 1,572,864
  unsigned short* Ua_bf = (unsigned short*)(wsB + 2 * szUk +
                                            (size_t)DD * 1024 * 4 +
                                            (size_t)DD * 768 * 4);     // 524,288
  float* bcat = (float*)((char*)Ua_bf + (size_t)DD * DD * 2);          // 8,192

  prep_wcat<<<(DD * 1024) / 256, 256, 0, stream>>>(Wa, W_hh, Wcat);
  prep_bcat<<<2048 / 256, 256, 0, stream>>>(ba, b_hh, bcat);
  prep_wih<<<(DD * 768) / 256, 256, 0, stream>>>(W_ih, Wih2);
  conv_bf<<<(BB * SS * DD) / (8 * 256), 256, 0, stream>>>(e_all, e_bfp);
  conv_bf<<<(DD * DD) / (8 * 256), 256, 0, stream>>>(Ua, Ua_bf);
  gemm_uk_mfma<<<dim3(DD / 128, (BB * SS) / 128), 256, 0, stream>>>(
      e_bfp, Ua_bf, bu, Uk2);

  decode_persistent<<<BB, 1024, 0, stream>>>(
      Uk2, e_bfp, Wcat, bcat, Wih2, b_ih, W_ih, e_last, target, Va_w,
      W_out, b_out, out_d, out_hT, out_attn);
}